// Round 11
// baseline (931.459 us; speedup 1.0000x reference)
//
#include <hip/hip_runtime.h>
#include <hip/hip_bf16.h>
#include <math.h>

// Problem constants
constexpr int BB   = 8;
constexpr int NN   = 4096;
constexpr int MM   = 1024;
constexpr int KK   = 16;
constexpr int COUT = 128;
#define RSQ 0.09f

__device__ __forceinline__ float dist2_exact(float ax, float ay, float az,
                                             float bx, float by, float bz) {
    // (a-b)^2 summed, no fma contraction: match numpy mul-then-add semantics
    float dx = __fsub_rn(ax, bx);
    float dy = __fsub_rn(ay, by);
    float dz = __fsub_rn(az, bz);
    return __fadd_rn(__fadd_rn(__fmul_rn(dx, dx), __fmul_rn(dy, dy)), __fmul_rn(dz, dz));
}

// DPP helper: returns neighbor value per CTRL; invalid source lanes keep self
// (old = self), which is the identity for max/min combines.
template<int CTRL>
__device__ __forceinline__ float dpp_mov_f(float v) {
    return __int_as_float(__builtin_amdgcn_update_dpp(
        __float_as_int(v), __float_as_int(v), CTRL, 0xF, 0xF, false));
}
template<int CTRL>
__device__ __forceinline__ unsigned dpp_mov_u(unsigned v) {
    return (unsigned)__builtin_amdgcn_update_dpp((int)v, (int)v, CTRL, 0xF, 0xF, false);
}

__device__ __forceinline__ float readlane_f(float v, int j) {
    return __int_as_float(__builtin_amdgcn_readlane(__float_as_int(v), j));
}

// ---------------------------------------------------------------------------
// Kernel 1: farthest point sampling — FROZEN at round-9 state (724 us).
// ---------------------------------------------------------------------------
__global__ __launch_bounds__(256, 1) void fps_kernel(const float* __restrict__ pos,
                                                     float* __restrict__ pos_s,
                                                     float* __restrict__ batch_s) {
    const int b    = blockIdx.x;
    const int tid  = threadIdx.x;
    const int lane = tid & 63;
    const int wave = tid >> 6;
    const float* pb = pos + (size_t)b * NN * 3;

    __shared__ float4 spos[NN];                       // 64 KB
    __shared__ int    shist[MM];                      // 4 KB selection history
    __shared__ unsigned long long slotK[2][4];        // packed keys, parity-buffered

    for (int i = tid; i < NN; i += 256)
        spos[i] = make_float4(pb[i * 3 + 0], pb[i * 3 + 1], pb[i * 3 + 2], 0.0f);
    for (int i = tid; i < MM; i += 256)
        batch_s[(size_t)b * MM + i] = (float)b;       // constant, written up front
    if (tid == 0) shist[0] = 0;
    if (tid < 8) slotK[tid >> 2][tid & 3] = 0ull;     // tag sentinel (m starts at 1)
    __syncthreads();

    // registers: 16 strided points per thread (p = tid + k*256)
    float px[16], py[16], pz[16], d[16];
    const float4 p0 = spos[0];
#pragma unroll
    for (int k = 0; k < 16; k++) {
        float4 pt = spos[tid + k * 256];
        px[k] = pt.x; py[k] = pt.y; pz[k] = pt.z;
        d[k] = dist2_exact(pt.x, pt.y, pt.z, p0.x, p0.y, p0.z);
    }
    // depth-4 max tree (value only; order-independent, exact)
    float bv;
    {
        float t1[8], t2[4];
#pragma unroll
        for (int k = 0; k < 8; k++) t1[k] = fmaxf(d[2 * k], d[2 * k + 1]);
#pragma unroll
        for (int k = 0; k < 4; k++) t2[k] = fmaxf(t1[2 * k], t1[2 * k + 1]);
        bv = fmaxf(fmaxf(t2[0], t2[1]), fmaxf(t2[2], t2[3]));
    }

    for (int m = 1; m < MM; m++) {
        const int par = m & 1;
        const unsigned tagm = (unsigned)m;            // m in [1,1023], fits 10 bits

        // ---- wave max (value only): 6 single-instr DPP steps ----
        float wv = bv;
        wv = fmaxf(wv, dpp_mov_f<0x111>(wv));   // row_shr:1
        wv = fmaxf(wv, dpp_mov_f<0x112>(wv));   // row_shr:2
        wv = fmaxf(wv, dpp_mov_f<0x114>(wv));   // row_shr:4
        wv = fmaxf(wv, dpp_mov_f<0x118>(wv));   // row_shr:8
        wv = fmaxf(wv, dpp_mov_f<0x142>(wv));   // row_bcast:15
        wv = fmaxf(wv, dpp_mov_f<0x143>(wv));   // row_bcast:31
        const float vstar = __int_as_float(
            __builtin_amdgcn_readlane(__float_as_int(wv), 63));

        // ---- lane's min-index achiever of bv: equality mask + ctz ----
        unsigned kmask = 0u;
#pragma unroll
        for (int k = 0; k < 16; k++)
            kmask |= (d[k] == bv) ? (1u << k) : 0u;   // bv is bit-exactly one of d[k]
        const int bi = tid + (__builtin_ctz(kmask) << 8);

        // ---- wave min point-index among achievers of vstar ----
        unsigned cand = (bv == vstar) ? (unsigned)bi : 0xFFFFFFFFu;
        cand = min(cand, dpp_mov_u<0x111>(cand));
        cand = min(cand, dpp_mov_u<0x112>(cand));
        cand = min(cand, dpp_mov_u<0x114>(cand));
        cand = min(cand, dpp_mov_u<0x118>(cand));
        cand = min(cand, dpp_mov_u<0x142>(cand));
        cand = min(cand, dpp_mov_u<0x143>(cand));     // full-wave min at lane 63

        if (lane == 63) {
            unsigned long long key =
                ((unsigned long long)(unsigned)__float_as_int(vstar) << 32)
                | (unsigned long long)(((4095u - cand) << 10) | tagm);
            __hip_atomic_store(&slotK[par][wave], key, __ATOMIC_RELAXED,
                               __HIP_MEMORY_SCOPE_WORKGROUP);
        }

        // ---- poll the 4 slots until all carry tag m ----
        unsigned long long k0, k1, k2, k3;
        for (;;) {
            k0 = __hip_atomic_load(&slotK[par][0], __ATOMIC_RELAXED, __HIP_MEMORY_SCOPE_WORKGROUP);
            k1 = __hip_atomic_load(&slotK[par][1], __ATOMIC_RELAXED, __HIP_MEMORY_SCOPE_WORKGROUP);
            k2 = __hip_atomic_load(&slotK[par][2], __ATOMIC_RELAXED, __HIP_MEMORY_SCOPE_WORKGROUP);
            k3 = __hip_atomic_load(&slotK[par][3], __ATOMIC_RELAXED, __HIP_MEMORY_SCOPE_WORKGROUP);
            bool ok = (((unsigned)k0 & 1023u) == tagm) &
                      (((unsigned)k1 & 1023u) == tagm) &
                      (((unsigned)k2 & 1023u) == tagm) &
                      (((unsigned)k3 & 1023u) == tagm);
            if (ok) break;
        }

        // ---- combine: u64 max (value desc, then index asc), unpack ----
        unsigned long long kA = (k0 > k1) ? k0 : k1;
        unsigned long long kB = (k2 > k3) ? k2 : k3;
        unsigned long long kk = (kA > kB) ? kA : kB;
        const int fi = 4095 - (int)(((unsigned)kk >> 10) & 4095u);

        if (tid == 0) shist[m] = fi;

        const float4 sp = spos[fi];           // one ds_read_b128, uniform
        if (m < MM - 1) {
#pragma unroll
            for (int k = 0; k < 16; k++) {
                float nd = dist2_exact(px[k], py[k], pz[k], sp.x, sp.y, sp.z);
                d[k] = fminf(d[k], nd);
            }
            float t1[8], t2[4];
#pragma unroll
            for (int k = 0; k < 8; k++) t1[k] = fmaxf(d[2 * k], d[2 * k + 1]);
#pragma unroll
            for (int k = 0; k < 4; k++) t2[k] = fmaxf(t1[2 * k], t1[2 * k + 1]);
            bv = fmaxf(fmaxf(t2[0], t2[1]), fmaxf(t2[2], t2[3]));
        }
    }

    // ---- write pos_s once, in parallel ----
    __syncthreads();
    for (int i = tid; i < MM; i += 256) {
        float4 sp = spos[shist[i]];
        size_t o = (size_t)b * MM + i;
        pos_s[o * 3 + 0] = sp.x;
        pos_s[o * 3 + 1] = sp.y;
        pos_s[o * 3 + 2] = sp.z;
    }
}

// ---------------------------------------------------------------------------
// Kernel 2: radius neighbors, first-K by index. One wave per query. (frozen)
// ---------------------------------------------------------------------------
__global__ __launch_bounds__(256) void radius_kernel(const float* __restrict__ pos,
                                                     const float* __restrict__ pos_s,
                                                     int* __restrict__ neigh,
                                                     int* __restrict__ counts) {
    const int q    = blockIdx.x * 4 + (threadIdx.x >> 6);
    const int lane = threadIdx.x & 63;
    const int b    = q >> 10;              // q / MM
    const float qx = pos_s[q * 3 + 0];
    const float qy = pos_s[q * 3 + 1];
    const float qz = pos_s[q * 3 + 2];
    const float* pb = pos + (size_t)b * NN * 3;

    int cnt = 0;
    for (int c = 0; c < NN / 64; c++) {
        int p = c * 64 + lane;
        float x = pb[p * 3 + 0], y = pb[p * 3 + 1], z = pb[p * 3 + 2];
        float d2 = dist2_exact(qx, qy, qz, x, y, z);
        bool val = (d2 <= RSQ);
        unsigned long long msk = __ballot(val);
        if (val) {
            int rank = __popcll(msk & ((1ull << lane) - 1ull));
            int slot = cnt + rank;
            if (slot < KK) neigh[q * KK + slot] = p;
        }
        cnt += __popcll(msk);
        if (cnt >= KK) break;
    }
    if (lane == 0) counts[q] = min(cnt, KK);
}

// ---------------------------------------------------------------------------
// Kernel 3: PointConv MLP (6->64->64->128) + masked max over K+1 edges.
//
// r10 -> r11: the mlp was LDS-ISSUE-bound (ds_read_b32 ~5.8cyc, b128 ~12cyc
// on the single per-CU LDS pipe -> ~190us). This version moves the h-vector
// broadcast OFF the LDS pipe: one WAVE owns one query end-to-end; h lives in
// VGPRs (lane = channel, one reg per edge); layer-2/3 use v_readlane (VALU,
// 4 SIMDs/CU) for the j-broadcast. ds ops per query: ~1750 -> 192 (only the
// per-lane W column reads). W1/b* in registers; weights staged once per
// 16 queries; ZERO per-query barriers (waves fully autonomous after staging).
// Validity semantics unchanged: first-K slots, g!=q removal, self always on.
// ---------------------------------------------------------------------------
__global__ __launch_bounds__(256, 2) void mlp_kernel(const float* __restrict__ x,
                                                     const float* __restrict__ pos,
                                                     const float* __restrict__ pos_s,
                                                     const float* __restrict__ W1,
                                                     const float* __restrict__ b1,
                                                     const float* __restrict__ W2,
                                                     const float* __restrict__ b2,
                                                     const float* __restrict__ W3,
                                                     const float* __restrict__ b3,
                                                     const int* __restrict__ neigh,
                                                     const int* __restrict__ counts,
                                                     float* __restrict__ out) {
    __shared__ float sW2[64 * 64];     // 16 KB
    __shared__ float sW3[64 * 128];    // 32 KB

    const int tid  = threadIdx.x;
    const int lane = tid & 63;
    const int wave = tid >> 6;

    // stage W2/W3 (float4 vectorized), once per 16 queries
    {
        const float4* s2 = (const float4*)W2;
        float4*       d2 = (float4*)sW2;
        for (int i = tid; i < 64 * 64 / 4; i += 256) d2[i] = s2[i];
        const float4* s3 = (const float4*)W3;
        float4*       d3 = (float4*)sW3;
        for (int i = tid; i < 64 * 128 / 4; i += 256) d3[i] = s3[i];
    }
    // per-lane weight registers (lane = channel)
    float w1c[6];
#pragma unroll
    for (int c = 0; c < 6; c++) w1c[c] = W1[c * 64 + lane];
    const float bb1  = b1[lane];
    const float bb2  = b2[lane];
    const float bb3a = b3[lane];
    const float bb3b = b3[64 + lane];
    __syncthreads();

    for (int qi = 0; qi < 4; qi++) {
        const int q = blockIdx.x * 16 + qi * 4 + wave;
        const int b = q >> 10;                    // q / MM
        const float qx = pos_s[q * 3 + 0];
        const float qy = pos_s[q * 3 + 1];
        const float qz = pos_s[q * 3 + 2];
        const int cnt = counts[q];

        // neighbor indices: 4x dwordx4
        const int4 n0 = *(const int4*)(neigh + (size_t)q * KK + 0);
        const int4 n1 = *(const int4*)(neigh + (size_t)q * KK + 4);
        const int4 n2 = *(const int4*)(neigh + (size_t)q * KK + 8);
        const int4 n3 = *(const int4*)(neigh + (size_t)q * KK + 12);
        const int nidx[16] = { n0.x, n0.y, n0.z, n0.w, n1.x, n1.y, n1.z, n1.w,
                               n2.x, n2.y, n2.z, n2.w, n3.x, n3.y, n3.z, n3.w };

        // ---- layer 1: h[e] in registers (lane = channel), validity mask ----
        float h[17];
        unsigned vmask = 1u << 16;                // self edge always valid
#pragma unroll
        for (int e = 0; e < 16; e++) {
            const int p = (e < cnt) ? nidx[e] : 0;     // clamp poisoned slots
            const int g = b * NN + p;
            if ((e < cnt) && (g != q)) vmask |= (1u << e);
            const float f0 = x[(size_t)g * 3 + 0];
            const float f1 = x[(size_t)g * 3 + 1];
            const float f2 = x[(size_t)g * 3 + 2];
            const float f3 = pos[(size_t)g * 3 + 0] - qx;
            const float f4 = pos[(size_t)g * 3 + 1] - qy;
            const float f5 = pos[(size_t)g * 3 + 2] - qz;
            float t = bb1 + f0 * w1c[0] + f1 * w1c[1] + f2 * w1c[2]
                          + f3 * w1c[3] + f4 * w1c[4] + f5 * w1c[5];
            h[e] = fmaxf(t, 0.0f);
        }
        {   // added self-loop: source row q of x/pos (PyG numeric quirk)
            const int g = q;
            const float f0 = x[(size_t)g * 3 + 0];
            const float f1 = x[(size_t)g * 3 + 1];
            const float f2 = x[(size_t)g * 3 + 2];
            const float f3 = pos[(size_t)g * 3 + 0] - qx;
            const float f4 = pos[(size_t)g * 3 + 1] - qy;
            const float f5 = pos[(size_t)g * 3 + 2] - qz;
            float t = bb1 + f0 * w1c[0] + f1 * w1c[1] + f2 * w1c[2]
                          + f3 * w1c[3] + f4 * w1c[4] + f5 * w1c[5];
            h[16] = fmaxf(t, 0.0f);
        }

        // ---- layer 2: readlane broadcast (VALU) + one ds W-read per j ----
        float acc[17];
#pragma unroll
        for (int e = 0; e < 17; e++) acc[e] = bb2;
#pragma unroll 2
        for (int j = 0; j < 64; j++) {
            const float wj = sW2[j * 64 + lane];
#pragma unroll
            for (int e = 0; e < 17; e++) {
                const float hj = readlane_f(h[e], j);
                acc[e] = __builtin_fmaf(hj, wj, acc[e]);
            }
        }
#pragma unroll
        for (int e = 0; e < 17; e++) h[e] = fmaxf(acc[e], 0.0f);

        // ---- layer 3: 2 channels/lane, readlane broadcast ----
        float a0[17], a1[17];
#pragma unroll
        for (int e = 0; e < 17; e++) { a0[e] = bb3a; a1[e] = bb3b; }
#pragma unroll 2
        for (int j = 0; j < 64; j++) {
            const float wa = sW3[j * 128 + lane];
            const float wb = sW3[j * 128 + 64 + lane];
#pragma unroll
            for (int e = 0; e < 17; e++) {
                const float hj = readlane_f(h[e], j);
                a0[e] = __builtin_fmaf(hj, wa, a0[e]);
                a1[e] = __builtin_fmaf(hj, wb, a1[e]);
            }
        }

        // ---- masked max over edges (order-insensitive) ----
        float m0 = -INFINITY, m1 = -INFINITY;
#pragma unroll
        for (int e = 0; e < 17; e++) {
            const bool v = (vmask >> e) & 1u;
            m0 = v ? fmaxf(m0, a0[e]) : m0;
            m1 = v ? fmaxf(m1, a1[e]) : m1;
        }
        out[(size_t)q * COUT + lane]      = m0;
        out[(size_t)q * COUT + 64 + lane] = m1;
    }
}

// ---------------------------------------------------------------------------
extern "C" void kernel_launch(void* const* d_in, const int* in_sizes, int n_in,
                              void* d_out, int out_size, void* d_ws, size_t ws_size,
                              hipStream_t stream) {
    const float* x   = (const float*)d_in[0];
    const float* pos = (const float*)d_in[1];
    // d_in[2] = batch (unused: layout is implicit)
    const float* W1 = (const float*)d_in[3];
    const float* b1 = (const float*)d_in[4];
    const float* W2 = (const float*)d_in[5];
    const float* b2 = (const float*)d_in[6];
    const float* W3 = (const float*)d_in[7];
    const float* b3 = (const float*)d_in[8];

    float* outF    = (float*)d_out;
    float* out     = outF;                                  // [B*M, 128]
    float* pos_s   = outF + (size_t)BB * MM * COUT;         // [B*M, 3]
    float* batch_s = pos_s + (size_t)BB * MM * 3;           // [B*M]

    int* neigh  = (int*)d_ws;                               // [B*M, K]
    int* counts = neigh + (size_t)BB * MM * KK;             // [B*M]

    fps_kernel<<<BB, 256, 0, stream>>>(pos, pos_s, batch_s);
    radius_kernel<<<BB * MM / 4, 256, 0, stream>>>(pos, pos_s, neigh, counts);
    mlp_kernel<<<BB * MM / 16, 256, 0, stream>>>(x, pos, pos_s, W1, b1, W2, b2, W3, b3,
                                                 neigh, counts, out);
}

// Round 12
// 920.498 us; speedup vs baseline: 1.0119x; 1.0119x over previous
//
#include <hip/hip_runtime.h>
#include <hip/hip_bf16.h>
#include <math.h>

// Problem constants
constexpr int BB   = 8;
constexpr int NN   = 4096;
constexpr int MM   = 1024;
constexpr int KK   = 16;
constexpr int COUT = 128;
#define RSQ 0.09f

__device__ __forceinline__ float dist2_exact(float ax, float ay, float az,
                                             float bx, float by, float bz) {
    // (a-b)^2 summed, no fma contraction: match numpy mul-then-add semantics
    float dx = __fsub_rn(ax, bx);
    float dy = __fsub_rn(ay, by);
    float dz = __fsub_rn(az, bz);
    return __fadd_rn(__fadd_rn(__fmul_rn(dx, dx), __fmul_rn(dy, dy)), __fmul_rn(dz, dz));
}

// DPP helper: returns neighbor value per CTRL; invalid source lanes keep self
// (old = self), which is the identity for max/min combines.
template<int CTRL>
__device__ __forceinline__ float dpp_mov_f(float v) {
    return __int_as_float(__builtin_amdgcn_update_dpp(
        __float_as_int(v), __float_as_int(v), CTRL, 0xF, 0xF, false));
}
template<int CTRL>
__device__ __forceinline__ unsigned dpp_mov_u(unsigned v) {
    return (unsigned)__builtin_amdgcn_update_dpp((int)v, (int)v, CTRL, 0xF, 0xF, false);
}

__device__ __forceinline__ float readlane_f(float v, int j) {
    return __int_as_float(__builtin_amdgcn_readlane(__float_as_int(v), j));
}

// ---------------------------------------------------------------------------
// Kernel 1: farthest point sampling — FROZEN at round-9 state (~723 us).
// ---------------------------------------------------------------------------
__global__ __launch_bounds__(256, 1) void fps_kernel(const float* __restrict__ pos,
                                                     float* __restrict__ pos_s,
                                                     float* __restrict__ batch_s) {
    const int b    = blockIdx.x;
    const int tid  = threadIdx.x;
    const int lane = tid & 63;
    const int wave = tid >> 6;
    const float* pb = pos + (size_t)b * NN * 3;

    __shared__ float4 spos[NN];                       // 64 KB
    __shared__ int    shist[MM];                      // 4 KB selection history
    __shared__ unsigned long long slotK[2][4];        // packed keys, parity-buffered

    for (int i = tid; i < NN; i += 256)
        spos[i] = make_float4(pb[i * 3 + 0], pb[i * 3 + 1], pb[i * 3 + 2], 0.0f);
    for (int i = tid; i < MM; i += 256)
        batch_s[(size_t)b * MM + i] = (float)b;       // constant, written up front
    if (tid == 0) shist[0] = 0;
    if (tid < 8) slotK[tid >> 2][tid & 3] = 0ull;     // tag sentinel (m starts at 1)
    __syncthreads();

    // registers: 16 strided points per thread (p = tid + k*256)
    float px[16], py[16], pz[16], d[16];
    const float4 p0 = spos[0];
#pragma unroll
    for (int k = 0; k < 16; k++) {
        float4 pt = spos[tid + k * 256];
        px[k] = pt.x; py[k] = pt.y; pz[k] = pt.z;
        d[k] = dist2_exact(pt.x, pt.y, pt.z, p0.x, p0.y, p0.z);
    }
    // depth-4 max tree (value only; order-independent, exact)
    float bv;
    {
        float t1[8], t2[4];
#pragma unroll
        for (int k = 0; k < 8; k++) t1[k] = fmaxf(d[2 * k], d[2 * k + 1]);
#pragma unroll
        for (int k = 0; k < 4; k++) t2[k] = fmaxf(t1[2 * k], t1[2 * k + 1]);
        bv = fmaxf(fmaxf(t2[0], t2[1]), fmaxf(t2[2], t2[3]));
    }

    for (int m = 1; m < MM; m++) {
        const int par = m & 1;
        const unsigned tagm = (unsigned)m;            // m in [1,1023], fits 10 bits

        // ---- wave max (value only): 6 single-instr DPP steps ----
        float wv = bv;
        wv = fmaxf(wv, dpp_mov_f<0x111>(wv));   // row_shr:1
        wv = fmaxf(wv, dpp_mov_f<0x112>(wv));   // row_shr:2
        wv = fmaxf(wv, dpp_mov_f<0x114>(wv));   // row_shr:4
        wv = fmaxf(wv, dpp_mov_f<0x118>(wv));   // row_shr:8
        wv = fmaxf(wv, dpp_mov_f<0x142>(wv));   // row_bcast:15
        wv = fmaxf(wv, dpp_mov_f<0x143>(wv));   // row_bcast:31
        const float vstar = __int_as_float(
            __builtin_amdgcn_readlane(__float_as_int(wv), 63));

        // ---- lane's min-index achiever of bv: equality mask + ctz ----
        unsigned kmask = 0u;
#pragma unroll
        for (int k = 0; k < 16; k++)
            kmask |= (d[k] == bv) ? (1u << k) : 0u;   // bv is bit-exactly one of d[k]
        const int bi = tid + (__builtin_ctz(kmask) << 8);

        // ---- wave min point-index among achievers of vstar ----
        unsigned cand = (bv == vstar) ? (unsigned)bi : 0xFFFFFFFFu;
        cand = min(cand, dpp_mov_u<0x111>(cand));
        cand = min(cand, dpp_mov_u<0x112>(cand));
        cand = min(cand, dpp_mov_u<0x114>(cand));
        cand = min(cand, dpp_mov_u<0x118>(cand));
        cand = min(cand, dpp_mov_u<0x142>(cand));
        cand = min(cand, dpp_mov_u<0x143>(cand));     // full-wave min at lane 63

        if (lane == 63) {
            unsigned long long key =
                ((unsigned long long)(unsigned)__float_as_int(vstar) << 32)
                | (unsigned long long)(((4095u - cand) << 10) | tagm);
            __hip_atomic_store(&slotK[par][wave], key, __ATOMIC_RELAXED,
                               __HIP_MEMORY_SCOPE_WORKGROUP);
        }

        // ---- poll the 4 slots until all carry tag m ----
        unsigned long long k0, k1, k2, k3;
        for (;;) {
            k0 = __hip_atomic_load(&slotK[par][0], __ATOMIC_RELAXED, __HIP_MEMORY_SCOPE_WORKGROUP);
            k1 = __hip_atomic_load(&slotK[par][1], __ATOMIC_RELAXED, __HIP_MEMORY_SCOPE_WORKGROUP);
            k2 = __hip_atomic_load(&slotK[par][2], __ATOMIC_RELAXED, __HIP_MEMORY_SCOPE_WORKGROUP);
            k3 = __hip_atomic_load(&slotK[par][3], __ATOMIC_RELAXED, __HIP_MEMORY_SCOPE_WORKGROUP);
            bool ok = (((unsigned)k0 & 1023u) == tagm) &
                      (((unsigned)k1 & 1023u) == tagm) &
                      (((unsigned)k2 & 1023u) == tagm) &
                      (((unsigned)k3 & 1023u) == tagm);
            if (ok) break;
        }

        // ---- combine: u64 max (value desc, then index asc), unpack ----
        unsigned long long kA = (k0 > k1) ? k0 : k1;
        unsigned long long kB = (k2 > k3) ? k2 : k3;
        unsigned long long kk = (kA > kB) ? kA : kB;
        const int fi = 4095 - (int)(((unsigned)kk >> 10) & 4095u);

        if (tid == 0) shist[m] = fi;

        const float4 sp = spos[fi];           // one ds_read_b128, uniform
        if (m < MM - 1) {
#pragma unroll
            for (int k = 0; k < 16; k++) {
                float nd = dist2_exact(px[k], py[k], pz[k], sp.x, sp.y, sp.z);
                d[k] = fminf(d[k], nd);
            }
            float t1[8], t2[4];
#pragma unroll
            for (int k = 0; k < 8; k++) t1[k] = fmaxf(d[2 * k], d[2 * k + 1]);
#pragma unroll
            for (int k = 0; k < 4; k++) t2[k] = fmaxf(t1[2 * k], t1[2 * k + 1]);
            bv = fmaxf(fmaxf(t2[0], t2[1]), fmaxf(t2[2], t2[3]));
        }
    }

    // ---- write pos_s once, in parallel ----
    __syncthreads();
    for (int i = tid; i < MM; i += 256) {
        float4 sp = spos[shist[i]];
        size_t o = (size_t)b * MM + i;
        pos_s[o * 3 + 0] = sp.x;
        pos_s[o * 3 + 1] = sp.y;
        pos_s[o * 3 + 2] = sp.z;
    }
}

// ---------------------------------------------------------------------------
// Kernel 2 (FUSED radius + MLP): one wave per query.
//
// r11 -> r12: (a) radius scan inlined (first-16-by-index, slots in a
// wave-private 16-int LDS array -> NO neigh/counts global round trip, one
// less launch); (b) __launch_bounds__(256,1): the layer-3 working set
// (h[17]+a0[17]+a1[17] = 51 floats) provably fits without scratch spill
// (r11's (256,2) 128-VGPR cap was borderline -> suspected spill = the
// unexplained ~120us); (c) radius L2-latency overlaps other waves' MLP VALU.
// Semantics byte-identical: <=RSQ membership, first-K slot order, slot
// occupancy by self-coincident points, g!=q numeric removal, self edge on.
// ---------------------------------------------------------------------------
__global__ __launch_bounds__(256, 1) void radius_mlp_kernel(const float* __restrict__ x,
                                                            const float* __restrict__ pos,
                                                            const float* __restrict__ pos_s,
                                                            const float* __restrict__ W1,
                                                            const float* __restrict__ b1,
                                                            const float* __restrict__ W2,
                                                            const float* __restrict__ b2,
                                                            const float* __restrict__ W3,
                                                            const float* __restrict__ b3,
                                                            float* __restrict__ out) {
    __shared__ float sW2[64 * 64];     // 16 KB
    __shared__ float sW3[64 * 128];    // 32 KB
    __shared__ int   nslot[4][16];     // per-wave neighbor slots (wave-private)

    const int tid  = threadIdx.x;
    const int lane = tid & 63;
    const int wave = tid >> 6;

    // stage W2/W3 (float4 vectorized), once per 4 queries
    {
        const float4* s2 = (const float4*)W2;
        float4*       d2 = (float4*)sW2;
        for (int i = tid; i < 64 * 64 / 4; i += 256) d2[i] = s2[i];
        const float4* s3 = (const float4*)W3;
        float4*       d3 = (float4*)sW3;
        for (int i = tid; i < 64 * 128 / 4; i += 256) d3[i] = s3[i];
    }
    // per-lane weight registers (lane = channel)
    float w1c[6];
#pragma unroll
    for (int c = 0; c < 6; c++) w1c[c] = W1[c * 64 + lane];
    const float bb1  = b1[lane];
    const float bb2  = b2[lane];
    const float bb3a = b3[lane];
    const float bb3b = b3[64 + lane];
    __syncthreads();

    const int q = blockIdx.x * 4 + wave;
    const int b = q >> 10;                    // q / MM
    const float qx = pos_s[q * 3 + 0];
    const float qy = pos_s[q * 3 + 1];
    const float qz = pos_s[q * 3 + 2];

    // ---- radius scan: first-16 by index within RSQ (identical semantics) ----
    if (lane < 16) nslot[wave][lane] = 0;     // wave-private init (no barrier)
    const float* pb = pos + (size_t)b * NN * 3;
    int cnt = 0;
    for (int c = 0; c < NN / 64; c++) {
        int p = c * 64 + lane;
        float px = pb[p * 3 + 0], py = pb[p * 3 + 1], pz = pb[p * 3 + 2];
        float d2 = dist2_exact(qx, qy, qz, px, py, pz);
        bool val = (d2 <= RSQ);
        unsigned long long msk = __ballot(val);
        if (val) {
            int rank = __popcll(msk & ((1ull << lane) - 1ull));
            int slot = cnt + rank;
            if (slot < KK) nslot[wave][slot] = p;
        }
        cnt += __popcll(msk);
        if (cnt >= KK) break;
    }
    const int cnt16 = min(cnt, KK);

    // neighbor indices (wave-uniform LDS broadcast reads)
    const int4 n0 = *(const int4*)&nslot[wave][0];
    const int4 n1 = *(const int4*)&nslot[wave][4];
    const int4 n2 = *(const int4*)&nslot[wave][8];
    const int4 n3 = *(const int4*)&nslot[wave][12];
    const int nidx[16] = { n0.x, n0.y, n0.z, n0.w, n1.x, n1.y, n1.z, n1.w,
                           n2.x, n2.y, n2.z, n2.w, n3.x, n3.y, n3.z, n3.w };

    // ---- layer 1: h[e] in registers (lane = channel), validity mask ----
    float h[17];
    unsigned vmask = 1u << 16;                // self edge always valid
#pragma unroll
    for (int e = 0; e < 16; e++) {
        const int p = (e < cnt16) ? nidx[e] : 0;
        const int g = b * NN + p;
        if ((e < cnt16) && (g != q)) vmask |= (1u << e);
        const float f0 = x[(size_t)g * 3 + 0];
        const float f1 = x[(size_t)g * 3 + 1];
        const float f2 = x[(size_t)g * 3 + 2];
        const float f3 = pos[(size_t)g * 3 + 0] - qx;
        const float f4 = pos[(size_t)g * 3 + 1] - qy;
        const float f5 = pos[(size_t)g * 3 + 2] - qz;
        float t = bb1 + f0 * w1c[0] + f1 * w1c[1] + f2 * w1c[2]
                      + f3 * w1c[3] + f4 * w1c[4] + f5 * w1c[5];
        h[e] = fmaxf(t, 0.0f);
    }
    {   // added self-loop: source row q of x/pos (PyG numeric quirk)
        const int g = q;
        const float f0 = x[(size_t)g * 3 + 0];
        const float f1 = x[(size_t)g * 3 + 1];
        const float f2 = x[(size_t)g * 3 + 2];
        const float f3 = pos[(size_t)g * 3 + 0] - qx;
        const float f4 = pos[(size_t)g * 3 + 1] - qy;
        const float f5 = pos[(size_t)g * 3 + 2] - qz;
        float t = bb1 + f0 * w1c[0] + f1 * w1c[1] + f2 * w1c[2]
                      + f3 * w1c[3] + f4 * w1c[4] + f5 * w1c[5];
        h[16] = fmaxf(t, 0.0f);
    }

    // ---- layer 2: readlane broadcast (VALU) + one ds W-read per j ----
    float acc[17];
#pragma unroll
    for (int e = 0; e < 17; e++) acc[e] = bb2;
#pragma unroll 2
    for (int j = 0; j < 64; j++) {
        const float wj = sW2[j * 64 + lane];
#pragma unroll
        for (int e = 0; e < 17; e++) {
            const float hj = readlane_f(h[e], j);
            acc[e] = __builtin_fmaf(hj, wj, acc[e]);
        }
    }
#pragma unroll
    for (int e = 0; e < 17; e++) h[e] = fmaxf(acc[e], 0.0f);

    // ---- layer 3: 2 channels/lane, readlane broadcast ----
    float a0[17], a1[17];
#pragma unroll
    for (int e = 0; e < 17; e++) { a0[e] = bb3a; a1[e] = bb3b; }
#pragma unroll 2
    for (int j = 0; j < 64; j++) {
        const float wa = sW3[j * 128 + lane];
        const float wb = sW3[j * 128 + 64 + lane];
#pragma unroll
        for (int e = 0; e < 17; e++) {
            const float hj = readlane_f(h[e], j);
            a0[e] = __builtin_fmaf(hj, wa, a0[e]);
            a1[e] = __builtin_fmaf(hj, wb, a1[e]);
        }
    }

    // ---- masked max over edges (order-insensitive) ----
    float m0 = -INFINITY, m1 = -INFINITY;
#pragma unroll
    for (int e = 0; e < 17; e++) {
        const bool v = (vmask >> e) & 1u;
        m0 = v ? fmaxf(m0, a0[e]) : m0;
        m1 = v ? fmaxf(m1, a1[e]) : m1;
    }
    out[(size_t)q * COUT + lane]      = m0;
    out[(size_t)q * COUT + 64 + lane] = m1;
}

// ---------------------------------------------------------------------------
extern "C" void kernel_launch(void* const* d_in, const int* in_sizes, int n_in,
                              void* d_out, int out_size, void* d_ws, size_t ws_size,
                              hipStream_t stream) {
    const float* x   = (const float*)d_in[0];
    const float* pos = (const float*)d_in[1];
    // d_in[2] = batch (unused: layout is implicit)
    const float* W1 = (const float*)d_in[3];
    const float* b1 = (const float*)d_in[4];
    const float* W2 = (const float*)d_in[5];
    const float* b2 = (const float*)d_in[6];
    const float* W3 = (const float*)d_in[7];
    const float* b3 = (const float*)d_in[8];

    float* outF    = (float*)d_out;
    float* out     = outF;                                  // [B*M, 128]
    float* pos_s   = outF + (size_t)BB * MM * COUT;         // [B*M, 3]
    float* batch_s = pos_s + (size_t)BB * MM * 3;           // [B*M]

    fps_kernel<<<BB, 256, 0, stream>>>(pos, pos_s, batch_s);
    radius_mlp_kernel<<<BB * MM / 4, 256, 0, stream>>>(x, pos, pos_s,
                                                       W1, b1, W2, b2, W3, b3, out);
}

// Round 13
// 895.337 us; speedup vs baseline: 1.0403x; 1.0281x over previous
//
#include <hip/hip_runtime.h>
#include <hip/hip_bf16.h>
#include <math.h>

// Problem constants
constexpr int BB   = 8;
constexpr int NN   = 4096;
constexpr int MM   = 1024;
constexpr int KK   = 16;
constexpr int COUT = 128;
#define RSQ 0.09f

__device__ __forceinline__ float dist2_exact(float ax, float ay, float az,
                                             float bx, float by, float bz) {
    // (a-b)^2 summed, no fma contraction: match numpy mul-then-add semantics
    float dx = __fsub_rn(ax, bx);
    float dy = __fsub_rn(ay, by);
    float dz = __fsub_rn(az, bz);
    return __fadd_rn(__fadd_rn(__fmul_rn(dx, dx), __fmul_rn(dy, dy)), __fmul_rn(dz, dz));
}

template<int CTRL>
__device__ __forceinline__ unsigned dpp_mov_u(unsigned v) {
    return (unsigned)__builtin_amdgcn_update_dpp((int)v, (int)v, CTRL, 0xF, 0xF, false);
}
__device__ __forceinline__ float readlane_f(float v, int j) {
    return __int_as_float(__builtin_amdgcn_readlane(__float_as_int(v), j));
}
__device__ __forceinline__ unsigned umax2(unsigned a, unsigned b) { return a > b ? a : b; }
__device__ __forceinline__ unsigned umin2(unsigned a, unsigned b) { return a < b ? a : b; }

// ---------------------------------------------------------------------------
// Kernel 1: farthest point sampling. One block per cloud, 256 thr, 16 pts/lane.
//
// r9 -> r13 (reduce-chain diet; update/poll/structure frozen):
//  Exactness basis: d = sum of squares >= +0.0 (never -0.0), so IEEE bit
//  patterns are order-monotone as unsigned -> all comparisons done in u32.
//  (1) value reduce: 4 within-row row_shr u32-max DPP steps (row maxima land
//      in lanes 15/31/47/63) + 4 v_readlane + 3 scalar max -> vstar in SGPR.
//      The two slow cross-row row_bcast steps and the broadcast readlane
//      are gone; scalar maxes run on the scalar pipe (overlap VALU).
//  (2) cand (min-index achiever) reduce: same 4-step + readlane + s_min
//      shape -> wave winner in SGPR (uniform); lane 0 packs/stores the key
//      from SGPRs only.
//  (3) kmask/ctz overlaps the 4-step value chain (independent).
// ---------------------------------------------------------------------------
__global__ __launch_bounds__(256, 1) void fps_kernel(const float* __restrict__ pos,
                                                     float* __restrict__ pos_s,
                                                     float* __restrict__ batch_s) {
    const int b    = blockIdx.x;
    const int tid  = threadIdx.x;
    const int lane = tid & 63;
    const int wave = tid >> 6;
    const float* pb = pos + (size_t)b * NN * 3;

    __shared__ float4 spos[NN];                       // 64 KB
    __shared__ int    shist[MM];                      // 4 KB selection history
    __shared__ unsigned long long slotK[2][4];        // packed keys, parity-buffered

    for (int i = tid; i < NN; i += 256)
        spos[i] = make_float4(pb[i * 3 + 0], pb[i * 3 + 1], pb[i * 3 + 2], 0.0f);
    for (int i = tid; i < MM; i += 256)
        batch_s[(size_t)b * MM + i] = (float)b;       // constant, written up front
    if (tid == 0) shist[0] = 0;
    if (tid < 8) slotK[tid >> 2][tid & 3] = 0ull;     // tag sentinel (m starts at 1)
    __syncthreads();

    // registers: 16 strided points per thread (p = tid + k*256)
    float px[16], py[16], pz[16], d[16];
    const float4 p0 = spos[0];
#pragma unroll
    for (int k = 0; k < 16; k++) {
        float4 pt = spos[tid + k * 256];
        px[k] = pt.x; py[k] = pt.y; pz[k] = pt.z;
        d[k] = dist2_exact(pt.x, pt.y, pt.z, p0.x, p0.y, p0.z);
    }
    // depth-4 max tree (value only; order-independent, exact)
    float bv;
    {
        float t1[8], t2[4];
#pragma unroll
        for (int k = 0; k < 8; k++) t1[k] = fmaxf(d[2 * k], d[2 * k + 1]);
#pragma unroll
        for (int k = 0; k < 4; k++) t2[k] = fmaxf(t1[2 * k], t1[2 * k + 1]);
        bv = fmaxf(fmaxf(t2[0], t2[1]), fmaxf(t2[2], t2[3]));
    }

    for (int m = 1; m < MM; m++) {
        const int par = m & 1;
        const unsigned tagm = (unsigned)m;            // m in [1,1023], fits 10 bits

        const unsigned bvb = __float_as_uint(bv);     // monotone bits (d >= +0)

        // ---- wave value max: 4 within-row DPP steps -> rows' maxima ----
        unsigned rv = bvb;
        rv = umax2(rv, dpp_mov_u<0x111>(rv));   // row_shr:1
        rv = umax2(rv, dpp_mov_u<0x112>(rv));   // row_shr:2
        rv = umax2(rv, dpp_mov_u<0x114>(rv));   // row_shr:4
        rv = umax2(rv, dpp_mov_u<0x118>(rv));   // row_shr:8
        // row maxima in lanes 15/31/47/63 -> scalar combine (SGPR result)
        const unsigned r0 = (unsigned)__builtin_amdgcn_readlane((int)rv, 15);
        const unsigned r1 = (unsigned)__builtin_amdgcn_readlane((int)rv, 31);
        const unsigned r2 = (unsigned)__builtin_amdgcn_readlane((int)rv, 47);
        const unsigned r3 = (unsigned)__builtin_amdgcn_readlane((int)rv, 63);
        const unsigned vstar = umax2(umax2(r0, r1), umax2(r2, r3));  // uniform

        // ---- lane's min-index achiever of bv (overlaps the chain above) ----
        unsigned kmask = 0u;
#pragma unroll
        for (int k = 0; k < 16; k++)
            kmask |= (d[k] == bv) ? (1u << k) : 0u;   // bv is bit-exactly one of d[k]
        const unsigned bi = (unsigned)(tid + (__builtin_ctz(kmask) << 8)); // = point idx

        // ---- wave min point-index among achievers of vstar ----
        unsigned cand = (bvb == vstar) ? bi : 0xFFFFFFFFu;
        cand = umin2(cand, dpp_mov_u<0x111>(cand));
        cand = umin2(cand, dpp_mov_u<0x112>(cand));
        cand = umin2(cand, dpp_mov_u<0x114>(cand));
        cand = umin2(cand, dpp_mov_u<0x118>(cand));
        const unsigned c0 = (unsigned)__builtin_amdgcn_readlane((int)cand, 15);
        const unsigned c1 = (unsigned)__builtin_amdgcn_readlane((int)cand, 31);
        const unsigned c2 = (unsigned)__builtin_amdgcn_readlane((int)cand, 47);
        const unsigned c3 = (unsigned)__builtin_amdgcn_readlane((int)cand, 63);
        const unsigned wcand = umin2(umin2(c0, c1), umin2(c2, c3));  // uniform

        if (lane == 0) {
            const unsigned long long key =
                ((unsigned long long)vstar << 32)
                | (unsigned long long)(((4095u - wcand) << 10) | tagm);
            __hip_atomic_store(&slotK[par][wave], key, __ATOMIC_RELAXED,
                               __HIP_MEMORY_SCOPE_WORKGROUP);
        }

        // ---- poll the 4 slots until all carry tag m (relaxed) ----
        unsigned long long k0, k1, k2, k3;
        for (;;) {
            k0 = __hip_atomic_load(&slotK[par][0], __ATOMIC_RELAXED, __HIP_MEMORY_SCOPE_WORKGROUP);
            k1 = __hip_atomic_load(&slotK[par][1], __ATOMIC_RELAXED, __HIP_MEMORY_SCOPE_WORKGROUP);
            k2 = __hip_atomic_load(&slotK[par][2], __ATOMIC_RELAXED, __HIP_MEMORY_SCOPE_WORKGROUP);
            k3 = __hip_atomic_load(&slotK[par][3], __ATOMIC_RELAXED, __HIP_MEMORY_SCOPE_WORKGROUP);
            bool ok = (((unsigned)k0 & 1023u) == tagm) &
                      (((unsigned)k1 & 1023u) == tagm) &
                      (((unsigned)k2 & 1023u) == tagm) &
                      (((unsigned)k3 & 1023u) == tagm);
            if (ok) break;
        }

        // ---- combine: u64 max (value desc, then index asc), unpack ----
        unsigned long long kA = (k0 > k1) ? k0 : k1;
        unsigned long long kB = (k2 > k3) ? k2 : k3;
        unsigned long long kk = (kA > kB) ? kA : kB;
        const int fi = 4095 - (int)(((unsigned)kk >> 10) & 4095u);

        if (tid == 0) shist[m] = fi;

        const float4 sp = spos[fi];           // one ds_read_b128, uniform
        if (m < MM - 1) {
#pragma unroll
            for (int k = 0; k < 16; k++) {
                float nd = dist2_exact(px[k], py[k], pz[k], sp.x, sp.y, sp.z);
                d[k] = fminf(d[k], nd);
            }
            float t1[8], t2[4];
#pragma unroll
            for (int k = 0; k < 8; k++) t1[k] = fmaxf(d[2 * k], d[2 * k + 1]);
#pragma unroll
            for (int k = 0; k < 4; k++) t2[k] = fmaxf(t1[2 * k], t1[2 * k + 1]);
            bv = fmaxf(fmaxf(t2[0], t2[1]), fmaxf(t2[2], t2[3]));
        }
    }

    // ---- write pos_s once, in parallel ----
    __syncthreads();
    for (int i = tid; i < MM; i += 256) {
        float4 sp = spos[shist[i]];
        size_t o = (size_t)b * MM + i;
        pos_s[o * 3 + 0] = sp.x;
        pos_s[o * 3 + 1] = sp.y;
        pos_s[o * 3 + 2] = sp.z;
    }
}

// ---------------------------------------------------------------------------
// Kernel 2 (FUSED radius + MLP): one wave per query. (frozen from r12)
// ---------------------------------------------------------------------------
__global__ __launch_bounds__(256, 1) void radius_mlp_kernel(const float* __restrict__ x,
                                                            const float* __restrict__ pos,
                                                            const float* __restrict__ pos_s,
                                                            const float* __restrict__ W1,
                                                            const float* __restrict__ b1,
                                                            const float* __restrict__ W2,
                                                            const float* __restrict__ b2,
                                                            const float* __restrict__ W3,
                                                            const float* __restrict__ b3,
                                                            float* __restrict__ out) {
    __shared__ float sW2[64 * 64];     // 16 KB
    __shared__ float sW3[64 * 128];    // 32 KB
    __shared__ int   nslot[4][16];     // per-wave neighbor slots (wave-private)

    const int tid  = threadIdx.x;
    const int lane = tid & 63;
    const int wave = tid >> 6;

    // stage W2/W3 (float4 vectorized), once per 4 queries
    {
        const float4* s2 = (const float4*)W2;
        float4*       d2 = (float4*)sW2;
        for (int i = tid; i < 64 * 64 / 4; i += 256) d2[i] = s2[i];
        const float4* s3 = (const float4*)W3;
        float4*       d3 = (float4*)sW3;
        for (int i = tid; i < 64 * 128 / 4; i += 256) d3[i] = s3[i];
    }
    // per-lane weight registers (lane = channel)
    float w1c[6];
#pragma unroll
    for (int c = 0; c < 6; c++) w1c[c] = W1[c * 64 + lane];
    const float bb1  = b1[lane];
    const float bb2  = b2[lane];
    const float bb3a = b3[lane];
    const float bb3b = b3[64 + lane];
    __syncthreads();

    const int q = blockIdx.x * 4 + wave;
    const int b = q >> 10;                    // q / MM
    const float qx = pos_s[q * 3 + 0];
    const float qy = pos_s[q * 3 + 1];
    const float qz = pos_s[q * 3 + 2];

    // ---- radius scan: first-16 by index within RSQ (identical semantics) ----
    if (lane < 16) nslot[wave][lane] = 0;     // wave-private init (no barrier)
    const float* pb = pos + (size_t)b * NN * 3;
    int cnt = 0;
    for (int c = 0; c < NN / 64; c++) {
        int p = c * 64 + lane;
        float px = pb[p * 3 + 0], py = pb[p * 3 + 1], pz = pb[p * 3 + 2];
        float d2 = dist2_exact(qx, qy, qz, px, py, pz);
        bool val = (d2 <= RSQ);
        unsigned long long msk = __ballot(val);
        if (val) {
            int rank = __popcll(msk & ((1ull << lane) - 1ull));
            int slot = cnt + rank;
            if (slot < KK) nslot[wave][slot] = p;
        }
        cnt += __popcll(msk);
        if (cnt >= KK) break;
    }
    const int cnt16 = min(cnt, KK);

    // neighbor indices (wave-uniform LDS broadcast reads)
    const int4 n0 = *(const int4*)&nslot[wave][0];
    const int4 n1 = *(const int4*)&nslot[wave][4];
    const int4 n2 = *(const int4*)&nslot[wave][8];
    const int4 n3 = *(const int4*)&nslot[wave][12];
    const int nidx[16] = { n0.x, n0.y, n0.z, n0.w, n1.x, n1.y, n1.z, n1.w,
                           n2.x, n2.y, n2.z, n2.w, n3.x, n3.y, n3.z, n3.w };

    // ---- layer 1: h[e] in registers (lane = channel), validity mask ----
    float h[17];
    unsigned vmask = 1u << 16;                // self edge always valid
#pragma unroll
    for (int e = 0; e < 16; e++) {
        const int p = (e < cnt16) ? nidx[e] : 0;
        const int g = b * NN + p;
        if ((e < cnt16) && (g != q)) vmask |= (1u << e);
        const float f0 = x[(size_t)g * 3 + 0];
        const float f1 = x[(size_t)g * 3 + 1];
        const float f2 = x[(size_t)g * 3 + 2];
        const float f3 = pos[(size_t)g * 3 + 0] - qx;
        const float f4 = pos[(size_t)g * 3 + 1] - qy;
        const float f5 = pos[(size_t)g * 3 + 2] - qz;
        float t = bb1 + f0 * w1c[0] + f1 * w1c[1] + f2 * w1c[2]
                      + f3 * w1c[3] + f4 * w1c[4] + f5 * w1c[5];
        h[e] = fmaxf(t, 0.0f);
    }
    {   // added self-loop: source row q of x/pos (PyG numeric quirk)
        const int g = q;
        const float f0 = x[(size_t)g * 3 + 0];
        const float f1 = x[(size_t)g * 3 + 1];
        const float f2 = x[(size_t)g * 3 + 2];
        const float f3 = pos[(size_t)g * 3 + 0] - qx;
        const float f4 = pos[(size_t)g * 3 + 1] - qy;
        const float f5 = pos[(size_t)g * 3 + 2] - qz;
        float t = bb1 + f0 * w1c[0] + f1 * w1c[1] + f2 * w1c[2]
                      + f3 * w1c[3] + f4 * w1c[4] + f5 * w1c[5];
        h[16] = fmaxf(t, 0.0f);
    }

    // ---- layer 2: readlane broadcast (VALU) + one ds W-read per j ----
    float acc[17];
#pragma unroll
    for (int e = 0; e < 17; e++) acc[e] = bb2;
#pragma unroll 2
    for (int j = 0; j < 64; j++) {
        const float wj = sW2[j * 64 + lane];
#pragma unroll
        for (int e = 0; e < 17; e++) {
            const float hj = readlane_f(h[e], j);
            acc[e] = __builtin_fmaf(hj, wj, acc[e]);
        }
    }
#pragma unroll
    for (int e = 0; e < 17; e++) h[e] = fmaxf(acc[e], 0.0f);

    // ---- layer 3: 2 channels/lane, readlane broadcast ----
    float a0[17], a1[17];
#pragma unroll
    for (int e = 0; e < 17; e++) { a0[e] = bb3a; a1[e] = bb3b; }
#pragma unroll 2
    for (int j = 0; j < 64; j++) {
        const float wa = sW3[j * 128 + lane];
        const float wb = sW3[j * 128 + 64 + lane];
#pragma unroll
        for (int e = 0; e < 17; e++) {
            const float hj = readlane_f(h[e], j);
            a0[e] = __builtin_fmaf(hj, wa, a0[e]);
            a1[e] = __builtin_fmaf(hj, wb, a1[e]);
        }
    }

    // ---- masked max over edges (order-insensitive) ----
    float m0 = -INFINITY, m1 = -INFINITY;
#pragma unroll
    for (int e = 0; e < 17; e++) {
        const bool v = (vmask >> e) & 1u;
        m0 = v ? fmaxf(m0, a0[e]) : m0;
        m1 = v ? fmaxf(m1, a1[e]) : m1;
    }
    out[(size_t)q * COUT + lane]      = m0;
    out[(size_t)q * COUT + 64 + lane] = m1;
}

// ---------------------------------------------------------------------------
extern "C" void kernel_launch(void* const* d_in, const int* in_sizes, int n_in,
                              void* d_out, int out_size, void* d_ws, size_t ws_size,
                              hipStream_t stream) {
    const float* x   = (const float*)d_in[0];
    const float* pos = (const float*)d_in[1];
    // d_in[2] = batch (unused: layout is implicit)
    const float* W1 = (const float*)d_in[3];
    const float* b1 = (const float*)d_in[4];
    const float* W2 = (const float*)d_in[5];
    const float* b2 = (const float*)d_in[6];
    const float* W3 = (const float*)d_in[7];
    const float* b3 = (const float*)d_in[8];

    float* outF    = (float*)d_out;
    float* out     = outF;                                  // [B*M, 128]
    float* pos_s   = outF + (size_t)BB * MM * COUT;         // [B*M, 3]
    float* batch_s = pos_s + (size_t)BB * MM * 3;           // [B*M]

    fps_kernel<<<BB, 256, 0, stream>>>(pos, pos_s, batch_s);
    radius_mlp_kernel<<<BB * MM / 4, 256, 0, stream>>>(x, pos, pos_s,
                                                       W1, b1, W2, b2, W3, b3, out);
}